// Round 1
// baseline (48179.010 us; speedup 1.0000x reference)
//
#include <hip/hip_runtime.h>
#include <hip/hip_bf16.h>

#define T_TOTAL 1024
#define BATCH   64
#define HID     512

__device__ __forceinline__ float fast_sigmoid(float x) {
    return 1.f / (1.f + __expf(-x));
}
__device__ __forceinline__ float fast_tanh(float x) {
    float ax = fabsf(x);
    float e  = __expf(-2.f * ax);
    float t  = (1.f - e) / (1.f + e);
    return copysignf(t, x);
}

// ---------------------------------------------------------------------------
// GEMM: C[m,n] = sum_k A[rowg(m),k] * W[n,k] + bias[n]
// A row-major [*, K], W row-major [N, K] (i.e. computes A @ W^T + bias).
// rowg maps chunk-local row m -> global row: (m/Tc)*T + t0 + (m%Tc), so a
// T-chunk of a [B,T,*] tensor can be processed with contiguous C rows.
// ---------------------------------------------------------------------------
template<int BM, int BN, int TM, int TN>
__global__ __launch_bounds__(256)
void gemm_bt_k(const float* __restrict__ A, const float* __restrict__ W,
               const float* __restrict__ bias, float* __restrict__ C,
               int K, int T, int Tc, int t0, int N)
{
    constexpr int BK = 16;
    constexpr int WSTR = BN + (BN / 32) * 4;   // group-of-32 pad to break conflicts
    static_assert(BM / TM == 16 && BN / TN == 16, "256 threads required");
    __shared__ float As[BK][BM + 4];
    __shared__ float Ws[BK][WSTR];

    const int tid = threadIdx.x;
    const int tx  = tid & 15;
    const int ty  = tid >> 4;
    const int m0  = blockIdx.y * BM;
    const int n0  = blockIdx.x * BN;
    const int nA  = tx * TN;
    const int nsw = nA + ((nA >> 5) << 2);

    float acc[TM][TN];
#pragma unroll
    for (int i = 0; i < TM; ++i)
#pragma unroll
        for (int j = 0; j < TN; ++j) acc[i][j] = 0.f;

    for (int k0 = 0; k0 < K; k0 += BK) {
        // stage A tile (transposed into As[k][m] for b128 reads along m)
#pragma unroll
        for (int i = 0; i < (BM * BK) / 1024; ++i) {
            int id = tid + (i << 8);
            int m  = id >> 2;
            int kq = (id & 3) << 2;
            int mloc = m0 + m;
            int rowg = (mloc / Tc) * T + t0 + (mloc % Tc);
            const float4 v = *reinterpret_cast<const float4*>(A + (size_t)rowg * K + k0 + kq);
            As[kq + 0][m] = v.x; As[kq + 1][m] = v.y;
            As[kq + 2][m] = v.z; As[kq + 3][m] = v.w;
        }
        // stage W tile
#pragma unroll
        for (int i = 0; i < (BN * BK) / 1024; ++i) {
            int id = tid + (i << 8);
            int n  = id >> 2;
            int kq = (id & 3) << 2;
            const float4 v = *reinterpret_cast<const float4*>(W + (size_t)(n0 + n) * K + k0 + kq);
            int np = n + ((n >> 5) << 2);
            Ws[kq + 0][np] = v.x; Ws[kq + 1][np] = v.y;
            Ws[kq + 2][np] = v.z; Ws[kq + 3][np] = v.w;
        }
        __syncthreads();
#pragma unroll
        for (int k = 0; k < BK; ++k) {
            float a[TM], b[TN];
#pragma unroll
            for (int i = 0; i < TM; i += 4)
                *reinterpret_cast<float4*>(&a[i]) =
                    *reinterpret_cast<const float4*>(&As[k][ty * TM + i]);
#pragma unroll
            for (int j = 0; j < TN; j += 4)
                *reinterpret_cast<float4*>(&b[j]) =
                    *reinterpret_cast<const float4*>(&Ws[k][nsw + j]);
#pragma unroll
            for (int i = 0; i < TM; ++i)
#pragma unroll
                for (int j = 0; j < TN; ++j)
                    acc[i][j] = fmaf(a[i], b[j], acc[i][j]);
        }
        __syncthreads();
    }
    // epilogue: add bias, store
#pragma unroll
    for (int i = 0; i < TM; ++i) {
        const size_t crow = (size_t)(m0 + ty * TM + i) * N + n0 + nA;
#pragma unroll
        for (int j = 0; j < TN; j += 4) {
            float4 bv = *reinterpret_cast<const float4*>(bias + n0 + nA + j);
            float4 v;
            v.x = acc[i][j + 0] + bv.x; v.y = acc[i][j + 1] + bv.y;
            v.z = acc[i][j + 2] + bv.z; v.w = acc[i][j + 3] + bv.w;
            *reinterpret_cast<float4*>(C + crow + j) = v;
        }
    }
}

// ---------------------------------------------------------------------------
// Persistent GRU scan kernel (one T-chunk of one layer).
// 256 blocks = 8 batch-groups (blockIdx%8 -> same XCD under round-robin
// dispatch) x 32 output-slices of 16 h-dims. Each thread permanently holds
// w_hh[3 gates][its dim d][its 32-wide K-chunk] in 24 float4 VGPRs, so the
// per-step [8,512]@[512,48] GEMM runs from registers + LDS-staged h.
// Cross-block h exchange: y buffer (global) + per-(group,t) counters with
// agent-scope release add / acquire spin.
// ---------------------------------------------------------------------------
__global__ __launch_bounds__(256)
void gru_scan(const float* __restrict__ xg,    // chunk-local [64][Tc][1536]
              const float* __restrict__ w_hh,  // [1536][512]
              const float* __restrict__ b_hh,  // [1536]
              float* __restrict__ y,           // [64][1024][512]
              unsigned int* __restrict__ cnt,  // [8][Tc], pre-zeroed
              int t0, int Tc)
{
    const int tid = threadIdx.x;
    const int grp = blockIdx.x & 7;       // batch group (XCD-local by heuristic)
    const int os  = blockIdx.x >> 3;      // output slice 0..31
    const int D0  = os << 4;              // first of 16 h-dims
    const int d   = tid & 15;             // this thread's dim within slice
    const int kc  = tid >> 4;             // this thread's K-chunk 0..15
    const int bg  = grp << 3;             // first batch row of group

    // h staging: [b][kc][36] padded so 4 kc's per wave hit distinct banks
    __shared__ float h_lds[8 * 576];
    __shared__ float part[16 * 392];      // [kc][g*128 + b*16 + d], pad 392
    __shared__ float hg_red[392];         // [g*128 + b*16 + d]

    // persistent weight fragment: w4[g][j] = w_hh[g*512+D0+d][kc*32 + 4j ..]
    float4 w4[3][8];
#pragma unroll
    for (int g = 0; g < 3; ++g) {
        const float* wr = w_hh + (size_t)(g * 512 + D0 + d) * 512 + kc * 32;
#pragma unroll
        for (int j = 0; j < 8; ++j)
            w4[g][j] = *reinterpret_cast<const float4*>(wr + (j << 2));
    }
    // bias values for the two reduce outputs this thread owns
    float bias0 = b_hh[((tid >> 7) * 512) + D0 + (tid & 15)];   // o = tid < 384 always
    float bias1 = 0.f;
    if (tid < 128) bias1 = b_hh[(((tid + 256) >> 7) * 512) + D0 + (tid & 15)];
    const int b_loc = tid >> 4;           // consumer threads (tid<128): batch row 0..7

    for (int tl = 0; tl < Tc; ++tl) {
        const int tg = t0 + tl;

        // issue this step's xg loads early (latency hidden behind spin + MAC)
        float xr = 0.f, xz = 0.f, xn = 0.f;
        if (tid < 128) {
            const size_t rowo = ((size_t)(bg + b_loc) * Tc + tl) * 1536 + D0 + d;
            xr = xg[rowo];
            xz = xg[rowo + 512];
            xn = xg[rowo + 1024];
        }

        // wait for previous step's h (all 32 blocks of this group)
        if (tl > 0) {
            const unsigned int* f = cnt + (grp * Tc + tl - 1);
            while (__hip_atomic_load(f, __ATOMIC_ACQUIRE, __HIP_MEMORY_SCOPE_AGENT) < 32u) {
                __builtin_amdgcn_s_sleep(1);
            }
        }

        // stage h_{t-1}[8][512] into LDS (zeros at t=0)
        if (tg == 0) {
#pragma unroll
            for (int i = 0; i < 4; ++i) {
                int idx = tid + (i << 8);
                int b = idx >> 7, k4 = idx & 127;
                int kcs = k4 >> 3, kk = (k4 & 7) << 2;
                *reinterpret_cast<float4*>(&h_lds[b * 576 + kcs * 36 + kk]) =
                    make_float4(0.f, 0.f, 0.f, 0.f);
            }
        } else {
#pragma unroll
            for (int i = 0; i < 4; ++i) {
                int idx = tid + (i << 8);
                int b = idx >> 7, k4 = idx & 127;
                const float4 v = *reinterpret_cast<const float4*>(
                    y + ((size_t)(bg + b) * T_TOTAL + (tg - 1)) * HID + (k4 << 2));
                int kcs = k4 >> 3, kk = (k4 & 7) << 2;
                *reinterpret_cast<float4*>(&h_lds[b * 576 + kcs * 36 + kk]) = v;
            }
        }
        __syncthreads();

        // register-resident MAC: acc[g][b] over this thread's 32-wide K chunk
        float acc0[8], acc1[8], acc2[8];
#pragma unroll
        for (int b = 0; b < 8; ++b) { acc0[b] = 0.f; acc1[b] = 0.f; acc2[b] = 0.f; }
        const float* hb_base = h_lds + kc * 36;
#pragma unroll
        for (int b = 0; b < 8; ++b) {
            const float* hb = hb_base + b * 576;
            float a0 = 0.f, a1 = 0.f, a2 = 0.f;
#pragma unroll
            for (int j = 0; j < 8; ++j) {
                const float4 h4 = *reinterpret_cast<const float4*>(hb + (j << 2));
                const float4 wa = w4[0][j], wb = w4[1][j], wc = w4[2][j];
                a0 = fmaf(wa.x, h4.x, a0); a0 = fmaf(wa.y, h4.y, a0);
                a0 = fmaf(wa.z, h4.z, a0); a0 = fmaf(wa.w, h4.w, a0);
                a1 = fmaf(wb.x, h4.x, a1); a1 = fmaf(wb.y, h4.y, a1);
                a1 = fmaf(wb.z, h4.z, a1); a1 = fmaf(wb.w, h4.w, a1);
                a2 = fmaf(wc.x, h4.x, a2); a2 = fmaf(wc.y, h4.y, a2);
                a2 = fmaf(wc.z, h4.z, a2); a2 = fmaf(wc.w, h4.w, a2);
            }
            acc0[b] = a0; acc1[b] = a1; acc2[b] = a2;
        }
        // write partials: part[kc][g*128 + b*16 + d]
        {
            float* pp = part + kc * 392 + d;
#pragma unroll
            for (int b = 0; b < 8; ++b) {
                pp[0 * 128 + b * 16] = acc0[b];
                pp[1 * 128 + b * 16] = acc1[b];
                pp[2 * 128 + b * 16] = acc2[b];
            }
        }
        __syncthreads();

        // reduce over 16 K-chunks: hg[g][b][d] + b_hh
        {
            float s = bias0;
#pragma unroll
            for (int q = 0; q < 16; ++q) s += part[q * 392 + tid];
            hg_red[tid] = s;
            if (tid < 128) {
                float s2 = bias1;
                const int o2 = tid + 256;
#pragma unroll
                for (int q = 0; q < 16; ++q) s2 += part[q * 392 + o2];
                hg_red[o2] = s2;
            }
        }
        __syncthreads();

        // gates + state update + publish
        if (tid < 128) {
            const float hr = hg_red[tid];
            const float hz = hg_red[128 + tid];
            const float hn = hg_red[256 + tid];
            const int D = D0 + d;
            const float hp = h_lds[b_loc * 576 + (D >> 5) * 36 + (D & 31)];
            const float r = fast_sigmoid(xr + hr);
            const float z = fast_sigmoid(xz + hz);
            const float nv = fast_tanh(xn + r * hn);
            const float h = (1.f - z) * nv + z * hp;
            y[((size_t)(bg + b_loc) * T_TOTAL + tg) * HID + D] = h;
        }
        __syncthreads();   // drains each thread's stores (vmcnt(0)) before barrier
        if (tid == 0) {
            __hip_atomic_fetch_add(cnt + grp * Tc + tl, 1u,
                                   __ATOMIC_RELEASE, __HIP_MEMORY_SCOPE_AGENT);
        }
    }
}

// ---------------------------------------------------------------------------
extern "C" void kernel_launch(void* const* d_in, const int* in_sizes, int n_in,
                              void* d_out, int out_size, void* d_ws, size_t ws_size,
                              hipStream_t stream)
{
    const float* x       = (const float*)d_in[0];
    const float* w_ih[2] = {(const float*)d_in[1], (const float*)d_in[5]};
    const float* w_hh[2] = {(const float*)d_in[2], (const float*)d_in[6]};
    const float* b_ih[2] = {(const float*)d_in[3], (const float*)d_in[7]};
    const float* b_hh[2] = {(const float*)d_in[4], (const float*)d_in[8]};
    const float* fc_w    = (const float*)d_in[9];
    const float* fc_b    = (const float*)d_in[10];
    float* out = (float*)d_out;

    const size_t Y_BYTES = (size_t)BATCH * T_TOTAL * HID * 4;   // 128 MiB
    int Tc = 256;
    while (Tc > 32) {
        size_t need = (size_t)BATCH * Tc * 1536 * 4 + Y_BYTES + (size_t)8 * Tc * 4;
        if (need <= ws_size) break;
        Tc >>= 1;
    }

    float* xg_buf      = (float*)d_ws;
    float* y_buf       = (float*)((char*)d_ws + (size_t)BATCH * Tc * 1536 * 4);
    unsigned int* cnt  = (unsigned int*)((char*)d_ws + (size_t)BATCH * Tc * 1536 * 4 + Y_BYTES);

    const int nchunks = T_TOTAL / Tc;
    for (int L = 0; L < 2; ++L) {
        const float* A = L ? y_buf : x;
        const int K    = L ? HID : 64;
        for (int c = 0; c < nchunks; ++c) {
            dim3 g1(1536 / 128, (BATCH * Tc) / 128);
            gemm_bt_k<128, 128, 8, 8><<<g1, 256, 0, stream>>>(
                A, w_ih[L], b_ih[L], xg_buf, K, T_TOTAL, Tc, c * Tc, 1536);
            hipMemsetAsync(cnt, 0, (size_t)8 * Tc * 4, stream);
            gru_scan<<<256, 256, 0, stream>>>(
                xg_buf, w_hh[L], b_hh[L], y_buf, cnt, c * Tc, Tc);
        }
    }
    // FC: out[m, i] = y[m, :] @ fc_w[i, :]^T + fc_b
    dim3 g2(64 / 64, (BATCH * T_TOTAL) / 128);
    gemm_bt_k<128, 64, 8, 4><<<g2, 256, 0, stream>>>(
        y_buf, fc_w, fc_b, out, HID, BATCH * T_TOTAL, BATCH * T_TOTAL, 0, 64);
}

// Round 2
// 12167.776 us; speedup vs baseline: 3.9596x; 3.9596x over previous
//
#include <hip/hip_runtime.h>
#include <hip/hip_bf16.h>

#define T_TOTAL 1024
#define BATCH   64
#define HID     512

__device__ __forceinline__ float fast_sigmoid(float x) {
    return 1.f / (1.f + __expf(-x));
}
__device__ __forceinline__ float fast_tanh(float x) {
    float ax = fabsf(x);
    float e  = __expf(-2.f * ax);
    float t  = (1.f - e) / (1.f + e);
    return copysignf(t, x);
}

// ---------------------------------------------------------------------------
// GEMM: C[m,n] = sum_k A[rowg(m),k] * W[n,k] + bias[n]
// A row-major [*, K], W row-major [N, K] (i.e. computes A @ W^T + bias).
// ---------------------------------------------------------------------------
template<int BM, int BN, int TM, int TN>
__global__ __launch_bounds__(256)
void gemm_bt_k(const float* __restrict__ A, const float* __restrict__ W,
               const float* __restrict__ bias, float* __restrict__ C,
               int K, int T, int Tc, int t0, int N)
{
    constexpr int BK = 16;
    constexpr int WSTR = BN + (BN / 32) * 4;
    static_assert(BM / TM == 16 && BN / TN == 16, "256 threads required");
    __shared__ float As[BK][BM + 4];
    __shared__ float Ws[BK][WSTR];

    const int tid = threadIdx.x;
    const int tx  = tid & 15;
    const int ty  = tid >> 4;
    const int m0  = blockIdx.y * BM;
    const int n0  = blockIdx.x * BN;
    const int nA  = tx * TN;
    const int nsw = nA + ((nA >> 5) << 2);

    float acc[TM][TN];
#pragma unroll
    for (int i = 0; i < TM; ++i)
#pragma unroll
        for (int j = 0; j < TN; ++j) acc[i][j] = 0.f;

    for (int k0 = 0; k0 < K; k0 += BK) {
#pragma unroll
        for (int i = 0; i < (BM * BK) / 1024; ++i) {
            int id = tid + (i << 8);
            int m  = id >> 2;
            int kq = (id & 3) << 2;
            int mloc = m0 + m;
            int rowg = (mloc / Tc) * T + t0 + (mloc % Tc);
            const float4 v = *reinterpret_cast<const float4*>(A + (size_t)rowg * K + k0 + kq);
            As[kq + 0][m] = v.x; As[kq + 1][m] = v.y;
            As[kq + 2][m] = v.z; As[kq + 3][m] = v.w;
        }
#pragma unroll
        for (int i = 0; i < (BN * BK) / 1024; ++i) {
            int id = tid + (i << 8);
            int n  = id >> 2;
            int kq = (id & 3) << 2;
            const float4 v = *reinterpret_cast<const float4*>(W + (size_t)(n0 + n) * K + k0 + kq);
            int np = n + ((n >> 5) << 2);
            Ws[kq + 0][np] = v.x; Ws[kq + 1][np] = v.y;
            Ws[kq + 2][np] = v.z; Ws[kq + 3][np] = v.w;
        }
        __syncthreads();
#pragma unroll
        for (int k = 0; k < BK; ++k) {
            float a[TM], b[TN];
#pragma unroll
            for (int i = 0; i < TM; i += 4)
                *reinterpret_cast<float4*>(&a[i]) =
                    *reinterpret_cast<const float4*>(&As[k][ty * TM + i]);
#pragma unroll
            for (int j = 0; j < TN; j += 4)
                *reinterpret_cast<float4*>(&b[j]) =
                    *reinterpret_cast<const float4*>(&Ws[k][nsw + j]);
#pragma unroll
            for (int i = 0; i < TM; ++i)
#pragma unroll
                for (int j = 0; j < TN; ++j)
                    acc[i][j] = fmaf(a[i], b[j], acc[i][j]);
        }
        __syncthreads();
    }
#pragma unroll
    for (int i = 0; i < TM; ++i) {
        const size_t crow = (size_t)(m0 + ty * TM + i) * N + n0 + nA;
#pragma unroll
        for (int j = 0; j < TN; j += 4) {
            float4 bv = *reinterpret_cast<const float4*>(bias + n0 + nA + j);
            float4 v;
            v.x = acc[i][j + 0] + bv.x; v.y = acc[i][j + 1] + bv.y;
            v.z = acc[i][j + 2] + bv.z; v.w = acc[i][j + 3] + bv.w;
            *reinterpret_cast<float4*>(C + crow + j) = v;
        }
    }
}

// ---------------------------------------------------------------------------
// Persistent GRU scan kernel (one T-chunk of one layer).
// 256 blocks = 8 batch-groups x 32 output-slices of 16 h-dims. Each thread
// permanently holds w_hh[3][d][32-wide K-chunk] in 24 float4 VGPRs.
//
// Cross-block h exchange uses ONLY relaxed agent-scope atomics (bypass L1,
// execute at the coherence point, NO cache invalidate/writeback — the R1
// acquire/release version invalidated the XCD L2 per poll, causing a 110 GB
// HBM over-fetch per dispatch). Ordering: producers' atomic stores drain at
// the __syncthreads() (compiler emits s_waitcnt vmcnt(0) before s_barrier)
// before tid0's relaxed counter add; consumers poll relaxed then load h via
// relaxed 64-bit atomic loads. hbuf is double-buffered by t&1; slot reuse at
// t+1 is safe because cnt[t]==32 implies every block consumed slot t-1.
// ---------------------------------------------------------------------------
__global__ __launch_bounds__(256)
void gru_scan(const float* __restrict__ xg,    // chunk-local [64][Tc][1536]
              const float* __restrict__ w_hh,  // [1536][512]
              const float* __restrict__ b_hh,  // [1536]
              float* __restrict__ y,           // [64][1024][512]
              float* __restrict__ hbuf,        // [8][2][8][512]
              unsigned int* __restrict__ cnt,  // [8][Tc], pre-zeroed
              int t0, int Tc)
{
    const int tid = threadIdx.x;
    const int grp = blockIdx.x & 7;
    const int os  = blockIdx.x >> 3;
    const int D0  = os << 4;
    const int d   = tid & 15;
    const int kc  = tid >> 4;
    const int bg  = grp << 3;

    __shared__ float h_lds[8 * 576];      // [b][kc][36] padded
    __shared__ float part[16 * 392];
    __shared__ float hg_red[392];

    float4 w4[3][8];
#pragma unroll
    for (int g = 0; g < 3; ++g) {
        const float* wr = w_hh + (size_t)(g * 512 + D0 + d) * 512 + kc * 32;
#pragma unroll
        for (int j = 0; j < 8; ++j)
            w4[g][j] = *reinterpret_cast<const float4*>(wr + (j << 2));
    }
    float bias0 = b_hh[((tid >> 7) * 512) + D0 + (tid & 15)];
    float bias1 = 0.f;
    if (tid < 128) bias1 = b_hh[(((tid + 256) >> 7) * 512) + D0 + (tid & 15)];
    const int b_loc = tid >> 4;

    for (int tl = 0; tl < Tc; ++tl) {
        const int tg = t0 + tl;

        // issue this step's xg loads early (latency hidden behind spin)
        float xr = 0.f, xz = 0.f, xn = 0.f;
        if (tid < 128) {
            const size_t rowo = ((size_t)(bg + b_loc) * Tc + tl) * 1536 + D0 + d;
            xr = xg[rowo];
            xz = xg[rowo + 512];
            xn = xg[rowo + 1024];
        }

        // wait for previous step's h (RELAXED poll — no cache invalidation)
        if (tl > 0) {
            const unsigned int* f = cnt + (grp * Tc + tl - 1);
            while (__hip_atomic_load(f, __ATOMIC_RELAXED, __HIP_MEMORY_SCOPE_AGENT) < 32u) {
                __builtin_amdgcn_s_sleep(2);
            }
            __builtin_amdgcn_sched_barrier(0);
        }

        // stage h_{t-1}[8][512] into LDS (zeros at t=0); relaxed atomic 8B
        // loads bypass L1 (no stale-slot hazard on the 2-deep hbuf)
        if (tg == 0) {
#pragma unroll
            for (int i = 0; i < 8; ++i) {
                int idx = tid + (i << 8);
                int b = idx >> 8, k2 = idx & 255;
                *reinterpret_cast<unsigned long long*>(
                    &h_lds[b * 576 + (k2 >> 4) * 36 + ((k2 & 15) << 1)]) = 0ull;
            }
        } else {
            const unsigned long long* hsrc = reinterpret_cast<const unsigned long long*>(
                hbuf + ((size_t)grp * 2 + ((tg - 1) & 1)) * 4096);
#pragma unroll
            for (int i = 0; i < 8; ++i) {
                int idx = tid + (i << 8);
                unsigned long long v = __hip_atomic_load(
                    hsrc + idx, __ATOMIC_RELAXED, __HIP_MEMORY_SCOPE_AGENT);
                int b = idx >> 8, k2 = idx & 255;
                *reinterpret_cast<unsigned long long*>(
                    &h_lds[b * 576 + (k2 >> 4) * 36 + ((k2 & 15) << 1)]) = v;
            }
        }
        __syncthreads();

        // register-resident MAC over this thread's 32-wide K chunk
        float acc0[8], acc1[8], acc2[8];
        const float* hb_base = h_lds + kc * 36;
#pragma unroll
        for (int b = 0; b < 8; ++b) {
            const float* hb = hb_base + b * 576;
            float a0 = 0.f, a1 = 0.f, a2 = 0.f;
#pragma unroll
            for (int j = 0; j < 8; ++j) {
                const float4 h4 = *reinterpret_cast<const float4*>(hb + (j << 2));
                const float4 wa = w4[0][j], wb = w4[1][j], wc = w4[2][j];
                a0 = fmaf(wa.x, h4.x, a0); a0 = fmaf(wa.y, h4.y, a0);
                a0 = fmaf(wa.z, h4.z, a0); a0 = fmaf(wa.w, h4.w, a0);
                a1 = fmaf(wb.x, h4.x, a1); a1 = fmaf(wb.y, h4.y, a1);
                a1 = fmaf(wb.z, h4.z, a1); a1 = fmaf(wb.w, h4.w, a1);
                a2 = fmaf(wc.x, h4.x, a2); a2 = fmaf(wc.y, h4.y, a2);
                a2 = fmaf(wc.z, h4.z, a2); a2 = fmaf(wc.w, h4.w, a2);
            }
            acc0[b] = a0; acc1[b] = a1; acc2[b] = a2;
        }
        {
            float* pp = part + kc * 392 + d;
#pragma unroll
            for (int b = 0; b < 8; ++b) {
                pp[0 * 128 + b * 16] = acc0[b];
                pp[1 * 128 + b * 16] = acc1[b];
                pp[2 * 128 + b * 16] = acc2[b];
            }
        }
        __syncthreads();

        // reduce over 16 K-chunks
        {
            float s = bias0;
#pragma unroll
            for (int q = 0; q < 16; ++q) s += part[q * 392 + tid];
            hg_red[tid] = s;
            if (tid < 128) {
                float s2 = bias1;
                const int o2 = tid + 256;
#pragma unroll
                for (int q = 0; q < 16; ++q) s2 += part[q * 392 + o2];
                hg_red[o2] = s2;
            }
        }
        __syncthreads();

        // gates + state update + publish
        float* hdst = hbuf + ((size_t)grp * 2 + (tg & 1)) * 4096;
        if (tid < 128) {
            const float hr = hg_red[tid];
            const float hz = hg_red[128 + tid];
            const float hn = hg_red[256 + tid];
            const int D = D0 + d;
            const float hp = h_lds[b_loc * 576 + (D >> 5) * 36 + (D & 31)];
            const float r = fast_sigmoid(xr + hr);
            const float z = fast_sigmoid(xz + hz);
            const float nv = fast_tanh(xn + r * hn);
            const float h = (1.f - z) * nv + z * hp;
            y[((size_t)(bg + b_loc) * T_TOTAL + tg) * HID + D] = h;
            __hip_atomic_store(hdst + b_loc * 512 + D, h,
                               __ATOMIC_RELAXED, __HIP_MEMORY_SCOPE_AGENT);
        }
        __syncthreads();   // drains vmcnt(0): h stores complete before the add
        if (tid == 0) {
            __hip_atomic_fetch_add(cnt + grp * Tc + tl, 1u,
                                   __ATOMIC_RELAXED, __HIP_MEMORY_SCOPE_AGENT);
        }
    }
}

// ---------------------------------------------------------------------------
extern "C" void kernel_launch(void* const* d_in, const int* in_sizes, int n_in,
                              void* d_out, int out_size, void* d_ws, size_t ws_size,
                              hipStream_t stream)
{
    const float* x       = (const float*)d_in[0];
    const float* w_ih[2] = {(const float*)d_in[1], (const float*)d_in[5]};
    const float* w_hh[2] = {(const float*)d_in[2], (const float*)d_in[6]};
    const float* b_ih[2] = {(const float*)d_in[3], (const float*)d_in[7]};
    const float* b_hh[2] = {(const float*)d_in[4], (const float*)d_in[8]};
    const float* fc_w    = (const float*)d_in[9];
    const float* fc_b    = (const float*)d_in[10];
    float* out = (float*)d_out;

    const size_t Y_BYTES = (size_t)BATCH * T_TOTAL * HID * 4;   // 128 MiB
    const size_t H_BYTES = (size_t)8 * 2 * 8 * 512 * 4;         // 256 KiB
    int Tc = 256;
    while (Tc > 32) {
        size_t need = (size_t)BATCH * Tc * 1536 * 4 + Y_BYTES + H_BYTES
                    + (size_t)8 * Tc * 4;
        if (need <= ws_size) break;
        Tc >>= 1;
    }

    char* p = (char*)d_ws;
    float* xg_buf = (float*)p;                 p += (size_t)BATCH * Tc * 1536 * 4;
    float* y_buf  = (float*)p;                 p += Y_BYTES;
    float* hbuf   = (float*)p;                 p += H_BYTES;
    unsigned int* cnt = (unsigned int*)p;

    const int nchunks = T_TOTAL / Tc;
    for (int L = 0; L < 2; ++L) {
        const float* A = L ? y_buf : x;
        const int K    = L ? HID : 64;
        for (int c = 0; c < nchunks; ++c) {
            dim3 g1(1536 / 128, (BATCH * Tc) / 128);
            gemm_bt_k<128, 128, 8, 8><<<g1, 256, 0, stream>>>(
                A, w_ih[L], b_ih[L], xg_buf, K, T_TOTAL, Tc, c * Tc, 1536);
            hipMemsetAsync(cnt, 0, (size_t)8 * Tc * 4, stream);
            gru_scan<<<256, 256, 0, stream>>>(
                xg_buf, w_hh[L], b_hh[L], y_buf, hbuf, cnt, c * Tc, Tc);
        }
    }
    dim3 g2(64 / 64, (BATCH * T_TOTAL) / 128);
    gemm_bt_k<128, 64, 8, 4><<<g2, 256, 0, stream>>>(
        y_buf, fc_w, fc_b, out, HID, BATCH * T_TOTAL, BATCH * T_TOTAL, 0, 64);
}

// Round 3
// 12017.199 us; speedup vs baseline: 4.0092x; 1.0125x over previous
//
#include <hip/hip_runtime.h>
#include <hip/hip_bf16.h>

#define T_TOTAL 1024
#define BATCH   64
#define HID     512

__device__ __forceinline__ float fast_sigmoid(float x) {
    return 1.f / (1.f + __expf(-x));
}
__device__ __forceinline__ float fast_tanh(float x) {
    float ax = fabsf(x);
    float e  = __expf(-2.f * ax);
    float t  = (1.f - e) / (1.f + e);
    return copysignf(t, x);
}

// ---------------------------------------------------------------------------
// GEMM: C[m,n] = sum_k A[rowg(m),k] * W[n,k] + bias[n]
// A row-major [*, K], W row-major [N, K] (i.e. computes A @ W^T + bias).
// __launch_bounds__(256,2): VGPR cap 256 — R2's default cap (72 VGPR) forced
// acc/frag spills; ~130 VGPR needed, 3 waves/EU still achievable.
// ---------------------------------------------------------------------------
template<int BM, int BN, int TM, int TN>
__global__ __launch_bounds__(256, 2)
void gemm_bt_k(const float* __restrict__ A, const float* __restrict__ W,
               const float* __restrict__ bias, float* __restrict__ C,
               int K, int T, int Tc, int t0, int N)
{
    constexpr int BK = 16;
    constexpr int WSTR = BN + (BN / 32) * 4;
    static_assert(BM / TM == 16 && BN / TN == 16, "256 threads required");
    __shared__ float As[BK][BM + 4];
    __shared__ float Ws[BK][WSTR];

    const int tid = threadIdx.x;
    const int tx  = tid & 15;
    const int ty  = tid >> 4;
    const int m0  = blockIdx.y * BM;
    const int n0  = blockIdx.x * BN;
    const int nA  = tx * TN;
    const int nsw = nA + ((nA >> 5) << 2);

    float acc[TM][TN];
#pragma unroll
    for (int i = 0; i < TM; ++i)
#pragma unroll
        for (int j = 0; j < TN; ++j) acc[i][j] = 0.f;

    for (int k0 = 0; k0 < K; k0 += BK) {
#pragma unroll
        for (int i = 0; i < (BM * BK) / 1024; ++i) {
            int id = tid + (i << 8);
            int m  = id >> 2;
            int kq = (id & 3) << 2;
            int mloc = m0 + m;
            int rowg = (mloc / Tc) * T + t0 + (mloc % Tc);
            const float4 v = *reinterpret_cast<const float4*>(A + (size_t)rowg * K + k0 + kq);
            As[kq + 0][m] = v.x; As[kq + 1][m] = v.y;
            As[kq + 2][m] = v.z; As[kq + 3][m] = v.w;
        }
#pragma unroll
        for (int i = 0; i < (BN * BK) / 1024; ++i) {
            int id = tid + (i << 8);
            int n  = id >> 2;
            int kq = (id & 3) << 2;
            const float4 v = *reinterpret_cast<const float4*>(W + (size_t)(n0 + n) * K + k0 + kq);
            int np = n + ((n >> 5) << 2);
            Ws[kq + 0][np] = v.x; Ws[kq + 1][np] = v.y;
            Ws[kq + 2][np] = v.z; Ws[kq + 3][np] = v.w;
        }
        __syncthreads();
#pragma unroll
        for (int k = 0; k < BK; ++k) {
            float a[TM], b[TN];
#pragma unroll
            for (int i = 0; i < TM; i += 4)
                *reinterpret_cast<float4*>(&a[i]) =
                    *reinterpret_cast<const float4*>(&As[k][ty * TM + i]);
#pragma unroll
            for (int j = 0; j < TN; j += 4)
                *reinterpret_cast<float4*>(&b[j]) =
                    *reinterpret_cast<const float4*>(&Ws[k][nsw + j]);
#pragma unroll
            for (int i = 0; i < TM; ++i)
#pragma unroll
                for (int j = 0; j < TN; ++j)
                    acc[i][j] = fmaf(a[i], b[j], acc[i][j]);
        }
        __syncthreads();
    }
#pragma unroll
    for (int i = 0; i < TM; ++i) {
        const size_t crow = (size_t)(m0 + ty * TM + i) * N + n0 + nA;
#pragma unroll
        for (int j = 0; j < TN; j += 4) {
            float4 bv = *reinterpret_cast<const float4*>(bias + n0 + nA + j);
            float4 v;
            v.x = acc[i][j + 0] + bv.x; v.y = acc[i][j + 1] + bv.y;
            v.z = acc[i][j + 2] + bv.z; v.w = acc[i][j + 3] + bv.w;
            *reinterpret_cast<float4*>(C + crow + j) = v;
        }
    }
}

// ---------------------------------------------------------------------------
// Persistent GRU scan kernel (one T-chunk of one layer).
// 256 blocks = 8 batch-groups x 32 output-slices of 16 h-dims. Each thread
// permanently holds w_hh[3][d][32-wide K-chunk] in 24 float4 VGPRs —
// __launch_bounds__(256,1) lifts the VGPR cap to 512 so they actually stay
// in VGPRs (R2: cap 80 forced the weight fragment into AGPR/scratch traffic
// inside the 768-FMA inner loop).
//
// Cross-block h exchange: TAGGED 64-bit words. Producer packs
// (tag<<32)|float_bits into one relaxed agent-scope 8B atomic store;
// consumers poll the data words themselves until the tag matches. One
// memory round trip on the critical path; no counter, no memset kernel, no
// post-store barrier (h_lds double-buffered). Overwrite safety of the
// 2-slot buffer: block P publishes t+1 only after consuming all tags t,
// which requires every block published t, which requires they consumed t-1.
// Tags (layer<<11)+tg are unique per launch; 0xAA ws-poison never matches.
// ---------------------------------------------------------------------------
__global__ __launch_bounds__(256, 1)
void gru_scan(const float* __restrict__ xg,    // chunk-local [64][Tc][1536]
              const float* __restrict__ w_hh,  // [1536][512]
              const float* __restrict__ b_hh,  // [1536]
              float* __restrict__ y,           // [64][1024][512]
              unsigned long long* __restrict__ hbuf, // [8 grp][2 slot][8 b][512]
              int t0, int Tc, int tagbase)
{
    const int tid = threadIdx.x;
    const int grp = blockIdx.x & 7;
    const int os  = blockIdx.x >> 3;
    const int D0  = os << 4;
    const int d   = tid & 15;
    const int kc  = tid >> 4;
    const int bg  = grp << 3;

    __shared__ float h_lds[2][8 * 576];   // double-buffered [b][kc][36]
    __shared__ float part[16 * 392];
    __shared__ float hg_red[392];

    float4 w4[3][8];
#pragma unroll
    for (int g = 0; g < 3; ++g) {
        const float* wr = w_hh + (size_t)(g * 512 + D0 + d) * 512 + kc * 32;
#pragma unroll
        for (int j = 0; j < 8; ++j)
            w4[g][j] = *reinterpret_cast<const float4*>(wr + (j << 2));
    }
    float bias0 = b_hh[((tid >> 7) * 512) + D0 + (tid & 15)];
    float bias1 = 0.f;
    if (tid < 128) bias1 = b_hh[(((tid + 256) >> 7) * 512) + D0 + (tid & 15)];
    const int b_loc = tid >> 4;

    for (int tl = 0; tl < Tc; ++tl) {
        const int tg = t0 + tl;
        float* hl = h_lds[tl & 1];

        // issue this step's xg loads early (latency hidden behind the poll)
        float xr = 0.f, xz = 0.f, xn = 0.f;
        if (tid < 128) {
            const size_t rowo = ((size_t)(bg + b_loc) * Tc + tl) * 1536 + D0 + d;
            xr = xg[rowo];
            xz = xg[rowo + 512];
            xn = xg[rowo + 1024];
        }

        // stage h_{t-1}[8][512] into LDS: poll tagged words until match
        if (tg == 0) {
#pragma unroll
            for (int i = 0; i < 16; ++i) {
                int idx = tid + (i << 8);
                int b = idx >> 9, D = idx & 511;
                hl[b * 576 + (D >> 5) * 36 + (D & 31)] = 0.f;
            }
        } else {
            const unsigned long long* hsrc =
                hbuf + (size_t)(grp * 2 + ((tg - 1) & 1)) * 4096;
            const unsigned int tagexp = (unsigned int)(tagbase + tl - 1);
            unsigned long long v[16];
            unsigned int pend = 0xffffu;
            while (pend) {
#pragma unroll
                for (int i = 0; i < 16; ++i)
                    if (pend & (1u << i))
                        v[i] = __hip_atomic_load(hsrc + tid + (i << 8),
                                __ATOMIC_RELAXED, __HIP_MEMORY_SCOPE_AGENT);
#pragma unroll
                for (int i = 0; i < 16; ++i)
                    if ((pend & (1u << i)) &&
                        (unsigned int)(v[i] >> 32) == tagexp) {
                        int idx = tid + (i << 8);
                        int b = idx >> 9, D = idx & 511;
                        union { unsigned int u; float f; } cv;
                        cv.u = (unsigned int)v[i];
                        hl[b * 576 + (D >> 5) * 36 + (D & 31)] = cv.f;
                        pend &= ~(1u << i);
                    }
                if (pend) __builtin_amdgcn_s_sleep(1);
            }
        }
        __syncthreads();

        // register-resident MAC over this thread's 32-wide K chunk
        float acc0[8], acc1[8], acc2[8];
        const float* hb_base = hl + kc * 36;
#pragma unroll
        for (int b = 0; b < 8; ++b) {
            const float* hb = hb_base + b * 576;
            float a0 = 0.f, a1 = 0.f, a2 = 0.f;
#pragma unroll
            for (int j = 0; j < 8; ++j) {
                const float4 h4 = *reinterpret_cast<const float4*>(hb + (j << 2));
                const float4 wa = w4[0][j], wb = w4[1][j], wc = w4[2][j];
                a0 = fmaf(wa.x, h4.x, a0); a0 = fmaf(wa.y, h4.y, a0);
                a0 = fmaf(wa.z, h4.z, a0); a0 = fmaf(wa.w, h4.w, a0);
                a1 = fmaf(wb.x, h4.x, a1); a1 = fmaf(wb.y, h4.y, a1);
                a1 = fmaf(wb.z, h4.z, a1); a1 = fmaf(wb.w, h4.w, a1);
                a2 = fmaf(wc.x, h4.x, a2); a2 = fmaf(wc.y, h4.y, a2);
                a2 = fmaf(wc.z, h4.z, a2); a2 = fmaf(wc.w, h4.w, a2);
            }
            acc0[b] = a0; acc1[b] = a1; acc2[b] = a2;
        }
        {
            float* pp = part + kc * 392 + d;
#pragma unroll
            for (int b = 0; b < 8; ++b) {
                pp[0 * 128 + b * 16] = acc0[b];
                pp[1 * 128 + b * 16] = acc1[b];
                pp[2 * 128 + b * 16] = acc2[b];
            }
        }
        __syncthreads();

        // reduce over 16 K-chunks
        {
            float s = bias0;
#pragma unroll
            for (int q = 0; q < 16; ++q) s += part[q * 392 + tid];
            hg_red[tid] = s;
            if (tid < 128) {
                float s2 = bias1;
                const int o2 = tid + 256;
#pragma unroll
                for (int q = 0; q < 16; ++q) s2 += part[q * 392 + o2];
                hg_red[o2] = s2;
            }
        }
        __syncthreads();

        // gates + state update + tagged publish (fire-and-forget, no barrier)
        if (tid < 128) {
            const float hr = hg_red[tid];
            const float hz = hg_red[128 + tid];
            const float hn = hg_red[256 + tid];
            const int D = D0 + d;
            const float hp = hl[b_loc * 576 + (D >> 5) * 36 + (D & 31)];
            const float r = fast_sigmoid(xr + hr);
            const float z = fast_sigmoid(xz + hz);
            const float nv = fast_tanh(xn + r * hn);
            const float h = (1.f - z) * nv + z * hp;
            y[((size_t)(bg + b_loc) * T_TOTAL + tg) * HID + D] = h;
            union { float f; unsigned int u; } cv; cv.f = h;
            const unsigned long long pk =
                ((unsigned long long)(unsigned int)(tagbase + tl) << 32) | cv.u;
            unsigned long long* hdst =
                hbuf + (size_t)(grp * 2 + (tg & 1)) * 4096 + b_loc * 512 + D;
            __hip_atomic_store(hdst, pk, __ATOMIC_RELAXED,
                               __HIP_MEMORY_SCOPE_AGENT);
        }
        // no trailing barrier: next iter stages into the other h_lds buffer;
        // `part` is only rewritten after the next stage barrier.
    }
}

// ---------------------------------------------------------------------------
extern "C" void kernel_launch(void* const* d_in, const int* in_sizes, int n_in,
                              void* d_out, int out_size, void* d_ws, size_t ws_size,
                              hipStream_t stream)
{
    const float* x       = (const float*)d_in[0];
    const float* w_ih[2] = {(const float*)d_in[1], (const float*)d_in[5]};
    const float* w_hh[2] = {(const float*)d_in[2], (const float*)d_in[6]};
    const float* b_ih[2] = {(const float*)d_in[3], (const float*)d_in[7]};
    const float* b_hh[2] = {(const float*)d_in[4], (const float*)d_in[8]};
    const float* fc_w    = (const float*)d_in[9];
    const float* fc_b    = (const float*)d_in[10];
    float* out = (float*)d_out;

    const size_t Y_BYTES = (size_t)BATCH * T_TOTAL * HID * 4;   // 128 MiB
    const size_t H_BYTES = (size_t)8 * 2 * 8 * 512 * 8;         // 512 KiB (u64)
    int Tc = 256;
    while (Tc > 32) {
        size_t need = (size_t)BATCH * Tc * 1536 * 4 + Y_BYTES + H_BYTES;
        if (need <= ws_size) break;
        Tc >>= 1;
    }

    char* p = (char*)d_ws;
    float* xg_buf = (float*)p;                 p += (size_t)BATCH * Tc * 1536 * 4;
    float* y_buf  = (float*)p;                 p += Y_BYTES;
    unsigned long long* hbuf = (unsigned long long*)p;

    const int nchunks = T_TOTAL / Tc;
    for (int L = 0; L < 2; ++L) {
        const float* A = L ? y_buf : x;
        const int K    = L ? HID : 64;
        for (int c = 0; c < nchunks; ++c) {
            dim3 g1(1536 / 128, (BATCH * Tc) / 128);
            gemm_bt_k<128, 128, 8, 8><<<g1, 256, 0, stream>>>(
                A, w_ih[L], b_ih[L], xg_buf, K, T_TOTAL, Tc, c * Tc, 1536);
            gru_scan<<<256, 256, 0, stream>>>(
                xg_buf, w_hh[L], b_hh[L], y_buf, hbuf,
                c * Tc, Tc, (L << 11) + c * Tc);
        }
    }
    dim3 g2(64 / 64, (BATCH * T_TOTAL) / 128);
    gemm_bt_k<128, 64, 8, 4><<<g2, 256, 0, stream>>>(
        y_buf, fc_w, fc_b, out, HID, BATCH * T_TOTAL, BATCH * T_TOTAL, 0, 64);
}

// Round 4
// 8474.156 us; speedup vs baseline: 5.6854x; 1.4181x over previous
//
#include <hip/hip_runtime.h>
#include <hip/hip_bf16.h>

#define T_TOTAL 1024
#define BATCH   64
#define HID     512

__device__ __forceinline__ float fast_sigmoid(float x) {
    return 1.f / (1.f + __expf(-x));
}
__device__ __forceinline__ float fast_tanh(float x) {
    float ax = fabsf(x);
    float e  = __expf(-2.f * ax);
    float t  = (1.f - e) / (1.f + e);
    return copysignf(t, x);
}

// ---------------------------------------------------------------------------
// GEMM: C[m,n] = sum_k A[rowg(m),k] * W[n,k] + bias[n]
// A row-major [*, K], W row-major [N, K] (i.e. computes A @ W^T + bias).
// ---------------------------------------------------------------------------
template<int BM, int BN, int TM, int TN>
__global__ __launch_bounds__(256, 2)
void gemm_bt_k(const float* __restrict__ A, const float* __restrict__ W,
               const float* __restrict__ bias, float* __restrict__ C,
               int K, int T, int Tc, int t0, int N)
{
    constexpr int BK = 16;
    constexpr int WSTR = BN + (BN / 32) * 4;
    static_assert(BM / TM == 16 && BN / TN == 16, "256 threads required");
    __shared__ float As[BK][BM + 4];
    __shared__ float Ws[BK][WSTR];

    const int tid = threadIdx.x;
    const int tx  = tid & 15;
    const int ty  = tid >> 4;
    const int m0  = blockIdx.y * BM;
    const int n0  = blockIdx.x * BN;
    const int nA  = tx * TN;
    const int nsw = nA + ((nA >> 5) << 2);

    float acc[TM][TN];
#pragma unroll
    for (int i = 0; i < TM; ++i)
#pragma unroll
        for (int j = 0; j < TN; ++j) acc[i][j] = 0.f;

    for (int k0 = 0; k0 < K; k0 += BK) {
#pragma unroll
        for (int i = 0; i < (BM * BK) / 1024; ++i) {
            int id = tid + (i << 8);
            int m  = id >> 2;
            int kq = (id & 3) << 2;
            int mloc = m0 + m;
            int rowg = (mloc / Tc) * T + t0 + (mloc % Tc);
            const float4 v = *reinterpret_cast<const float4*>(A + (size_t)rowg * K + k0 + kq);
            As[kq + 0][m] = v.x; As[kq + 1][m] = v.y;
            As[kq + 2][m] = v.z; As[kq + 3][m] = v.w;
        }
#pragma unroll
        for (int i = 0; i < (BN * BK) / 1024; ++i) {
            int id = tid + (i << 8);
            int n  = id >> 2;
            int kq = (id & 3) << 2;
            const float4 v = *reinterpret_cast<const float4*>(W + (size_t)(n0 + n) * K + k0 + kq);
            int np = n + ((n >> 5) << 2);
            Ws[kq + 0][np] = v.x; Ws[kq + 1][np] = v.y;
            Ws[kq + 2][np] = v.z; Ws[kq + 3][np] = v.w;
        }
        __syncthreads();
#pragma unroll
        for (int k = 0; k < BK; ++k) {
            float a[TM], b[TN];
#pragma unroll
            for (int i = 0; i < TM; i += 4)
                *reinterpret_cast<float4*>(&a[i]) =
                    *reinterpret_cast<const float4*>(&As[k][ty * TM + i]);
#pragma unroll
            for (int j = 0; j < TN; j += 4)
                *reinterpret_cast<float4*>(&b[j]) =
                    *reinterpret_cast<const float4*>(&Ws[k][nsw + j]);
#pragma unroll
            for (int i = 0; i < TM; ++i)
#pragma unroll
                for (int j = 0; j < TN; ++j)
                    acc[i][j] = fmaf(a[i], b[j], acc[i][j]);
        }
        __syncthreads();
    }
#pragma unroll
    for (int i = 0; i < TM; ++i) {
        const size_t crow = (size_t)(m0 + ty * TM + i) * N + n0 + nA;
#pragma unroll
        for (int j = 0; j < TN; j += 4) {
            float4 bv = *reinterpret_cast<const float4*>(bias + n0 + nA + j);
            float4 v;
            v.x = acc[i][j + 0] + bv.x; v.y = acc[i][j + 1] + bv.y;
            v.z = acc[i][j + 2] + bv.z; v.w = acc[i][j + 3] + bv.w;
            *reinterpret_cast<float4*>(C + crow + j) = v;
        }
    }
}

// ---------------------------------------------------------------------------
// Persistent GRU scan (one T-chunk of one layer).
// NEW topology (R4): 16 groups x 16 blocks x 512 threads (was 8x32x256).
//   - group owns 4 batch rows; block owns 32 h-dims; thread (d=tid&31,
//     kc=tid>>5) holds w_hh[3][D0+d][kc*32..+32] = 96 floats in VGPRs.
//   - Exchange per step: 16 publishers (was 32), 16 KB gathered (was 32 KB),
//     poll width 4 words/thread (was 16) -> ~4x less fabric contention.
//   - 2 waves/SIMD (was 1): poll + LDS latency overlaps with FMA issue.
// Same relaxed tagged-word protocol as R3 (one mem round trip, no counter,
// no trailing barrier; 2-slot hbuf overwrite-safe by induction on step).
// ---------------------------------------------------------------------------
__global__ __launch_bounds__(512, 2)
void gru_scan(const float* __restrict__ xg,    // chunk-local [64][Tc][1536]
              const float* __restrict__ w_hh,  // [1536][512]
              const float* __restrict__ b_hh,  // [1536]
              float* __restrict__ y,           // [64][1024][512]
              unsigned long long* __restrict__ hbuf, // [16 grp][2 slot][4 b][512]
              int t0, int Tc, int tagbase)
{
    const int tid = threadIdx.x;
    const int grp = blockIdx.x & 15;      // same XCD under round-robin dispatch
    const int os  = blockIdx.x >> 4;      // output slice 0..15
    const int D0  = os << 5;              // 32 h-dims per block
    const int d   = tid & 31;
    const int kc  = tid >> 5;             // 0..15
    const int bg  = grp << 2;             // 4 batch rows per group

    __shared__ float h_lds[2][4 * 576];   // [slot][b][kc][36] padded
    __shared__ float part[16 * 392];      // [kc][g*128 + b*32 + d] (384 used)
    __shared__ float hg_red[392];         // 384 used

    // persistent weights: w4[g][j] = w_hh[g*512+D0+d][kc*32 + 4j ..]
    float4 w4[3][8];
#pragma unroll
    for (int g = 0; g < 3; ++g) {
        const float* wr = w_hh + (size_t)(g * 512 + D0 + d) * 512 + kc * 32;
#pragma unroll
        for (int j = 0; j < 8; ++j)
            w4[g][j] = *reinterpret_cast<const float4*>(wr + (j << 2));
    }
    // reduce-phase bias: thread o<384 owns output o = g*128 + b*32 + d
    float bias0 = (tid < 384) ? b_hh[(tid >> 7) * 512 + D0 + (tid & 31)] : 0.f;
    const int b_loc = tid >> 5;           // gate threads (tid<128): row 0..3

    for (int tl = 0; tl < Tc; ++tl) {
        const int tg = t0 + tl;
        float* hl = h_lds[tl & 1];

        // issue this step's xg loads early (hidden behind the poll)
        float xr = 0.f, xz = 0.f, xn = 0.f;
        if (tid < 128) {
            const size_t rowo = ((size_t)(bg + b_loc) * Tc + tl) * 1536 + D0 + d;
            xr = xg[rowo];
            xz = xg[rowo + 512];
            xn = xg[rowo + 1024];
        }

        // stage h_{t-1}[4][512] into LDS: poll tagged words until match
        if (tg == 0) {
#pragma unroll
            for (int i = 0; i < 4; ++i) {
                int idx = tid + (i << 9);
                int b = idx >> 9, D = idx & 511;
                hl[b * 576 + (D >> 5) * 36 + (D & 31)] = 0.f;
            }
        } else {
            const unsigned long long* hsrc =
                hbuf + (size_t)(grp * 2 + ((tg - 1) & 1)) * 2048;
            const unsigned int tagexp = (unsigned int)(tagbase + tl - 1);
            unsigned long long v[4];
            unsigned int pend = 0xFu;
            while (pend) {
#pragma unroll
                for (int i = 0; i < 4; ++i)
                    if (pend & (1u << i))
                        v[i] = __hip_atomic_load(hsrc + tid + (i << 9),
                                __ATOMIC_RELAXED, __HIP_MEMORY_SCOPE_AGENT);
#pragma unroll
                for (int i = 0; i < 4; ++i)
                    if ((pend & (1u << i)) &&
                        (unsigned int)(v[i] >> 32) == tagexp) {
                        int idx = tid + (i << 9);
                        int b = idx >> 9, D = idx & 511;
                        union { unsigned int u; float f; } cv;
                        cv.u = (unsigned int)v[i];
                        hl[b * 576 + (D >> 5) * 36 + (D & 31)] = cv.f;
                        pend &= ~(1u << i);
                    }
                if (pend) __builtin_amdgcn_s_sleep(1);
            }
        }
        __syncthreads();

        // register-resident MAC: acc[g][b] over this thread's 32-wide K chunk
        float acc[3][4];
#pragma unroll
        for (int g = 0; g < 3; ++g)
#pragma unroll
            for (int b = 0; b < 4; ++b) acc[g][b] = 0.f;
        const float* hb_base = hl + kc * 36;
#pragma unroll
        for (int j = 0; j < 8; ++j) {
            float4 h4[4];
#pragma unroll
            for (int b = 0; b < 4; ++b)
                h4[b] = *reinterpret_cast<const float4*>(hb_base + b * 576 + (j << 2));
#pragma unroll
            for (int g = 0; g < 3; ++g) {
                const float4 w = w4[g][j];
#pragma unroll
                for (int b = 0; b < 4; ++b) {
                    acc[g][b] = fmaf(w.x, h4[b].x, acc[g][b]);
                    acc[g][b] = fmaf(w.y, h4[b].y, acc[g][b]);
                    acc[g][b] = fmaf(w.z, h4[b].z, acc[g][b]);
                    acc[g][b] = fmaf(w.w, h4[b].w, acc[g][b]);
                }
            }
        }
        {
            float* pp = part + kc * 392 + d;
#pragma unroll
            for (int g = 0; g < 3; ++g)
#pragma unroll
                for (int b = 0; b < 4; ++b)
                    pp[g * 128 + b * 32] = acc[g][b];
        }
        __syncthreads();

        // reduce over 16 K-chunks: output o = g*128 + b*32 + d
        if (tid < 384) {
            float s = bias0;
#pragma unroll
            for (int q = 0; q < 16; ++q) s += part[q * 392 + tid];
            hg_red[tid] = s;
        }
        __syncthreads();

        // gates + state update + tagged publish (fire-and-forget)
        if (tid < 128) {
            const float hr = hg_red[tid];
            const float hz = hg_red[128 + tid];
            const float hn = hg_red[256 + tid];
            const int D = D0 + d;
            const float hp = hl[b_loc * 576 + os * 36 + d];
            const float r = fast_sigmoid(xr + hr);
            const float z = fast_sigmoid(xz + hz);
            const float nv = fast_tanh(xn + r * hn);
            const float h = (1.f - z) * nv + z * hp;
            y[((size_t)(bg + b_loc) * T_TOTAL + tg) * HID + D] = h;
            union { float f; unsigned int u; } cv; cv.f = h;
            const unsigned long long pk =
                ((unsigned long long)(unsigned int)(tagbase + tl) << 32) | cv.u;
            unsigned long long* hdst =
                hbuf + (size_t)(grp * 2 + (tg & 1)) * 2048 + b_loc * 512 + D;
            __hip_atomic_store(hdst, pk, __ATOMIC_RELAXED,
                               __HIP_MEMORY_SCOPE_AGENT);
        }
        // no trailing barrier: next iter stages into the other h_lds buffer;
        // `part` is only rewritten after the next stage barrier.
    }
}

// ---------------------------------------------------------------------------
extern "C" void kernel_launch(void* const* d_in, const int* in_sizes, int n_in,
                              void* d_out, int out_size, void* d_ws, size_t ws_size,
                              hipStream_t stream)
{
    const float* x       = (const float*)d_in[0];
    const float* w_ih[2] = {(const float*)d_in[1], (const float*)d_in[5]};
    const float* w_hh[2] = {(const float*)d_in[2], (const float*)d_in[6]};
    const float* b_ih[2] = {(const float*)d_in[3], (const float*)d_in[7]};
    const float* b_hh[2] = {(const float*)d_in[4], (const float*)d_in[8]};
    const float* fc_w    = (const float*)d_in[9];
    const float* fc_b    = (const float*)d_in[10];
    float* out = (float*)d_out;

    const size_t Y_BYTES = (size_t)BATCH * T_TOTAL * HID * 4;   // 128 MiB
    const size_t H_BYTES = (size_t)16 * 2 * 4 * 512 * 8;        // 512 KiB (u64)
    int Tc = 256;
    while (Tc > 32) {
        size_t need = (size_t)BATCH * Tc * 1536 * 4 + Y_BYTES + H_BYTES;
        if (need <= ws_size) break;
        Tc >>= 1;
    }

    char* p = (char*)d_ws;
    float* xg_buf = (float*)p;                 p += (size_t)BATCH * Tc * 1536 * 4;
    float* y_buf  = (float*)p;                 p += Y_BYTES;
    unsigned long long* hbuf = (unsigned long long*)p;

    const int nchunks = T_TOTAL / Tc;
    for (int L = 0; L < 2; ++L) {
        const float* A = L ? y_buf : x;
        const int K    = L ? HID : 64;
        for (int c = 0; c < nchunks; ++c) {
            dim3 g1(1536 / 128, (BATCH * Tc) / 128);
            gemm_bt_k<128, 128, 8, 8><<<g1, 256, 0, stream>>>(
                A, w_ih[L], b_ih[L], xg_buf, K, T_TOTAL, Tc, c * Tc, 1536);
            gru_scan<<<256, 512, 0, stream>>>(
                xg_buf, w_hh[L], b_hh[L], y_buf, hbuf,
                c * Tc, Tc, (L << 11) + c * Tc);
        }
    }
    dim3 g2(64 / 64, (BATCH * T_TOTAL) / 128);
    gemm_bt_k<128, 64, 8, 4><<<g2, 256, 0, stream>>>(
        y_buf, fc_w, fc_b, out, HID, BATCH * T_TOTAL, BATCH * T_TOTAL, 0, 64);
}